// Round 5
// baseline (374.781 us; speedup 1.0000x reference)
//
#include <hip/hip_runtime.h>
#include <hip/hip_bf16.h>
#include <cstdint>

// B=384, S=128, E=512, H=4, D=128. out = softmax((x Wq)(x Wk)^T) (x Wv) Wo
// Round 9: k_core restructured for occupancy: V is no longer LDS-staged (PV's
// B-fragments read directly from the block-private 32 KB vtb panel via L1/L2,
// catalog lesson "don't stage what cache-fits"). LDS 64->32 KB, launch_bounds
// (512,6) -> 3 blocks/CU (was 2). P and O reuse SK after the post-QK^T
// barrier (wave-local band -> lgkmcnt-only sync). k_prep/k_qkv/k_out
// unchanged (k_qkv at m97 plateau, 92.8 us).

#define EMB 512

typedef __attribute__((ext_vector_type(4))) float    f32x4;
typedef __attribute__((ext_vector_type(8))) _Float16 f16x8;

#define MFMA16(a, b, c) __builtin_amdgcn_mfma_f32_16x16x32_f16((a), (b), (c), 0, 0, 0)

// XOR swizzle: element (row,col) of a [*][stride] f16 tile at
// row*stride + (col ^ (((row>>2)&3)<<4)). C-writebacks conflict-free,
// b128 fragment reads conflict-ideal despite stride % 128B == 0.
__device__ __forceinline__ int swz128(int row, int col) {
    return row * 128 + (col ^ (((row >> 2) & 3) << 4));
}
__device__ __forceinline__ int swz64(int row, int col) {
    return row * 64 + (col ^ (((row >> 2) & 3) << 4));
}

__device__ __forceinline__ void gld_lds16(const _Float16* g, _Float16* l) {
    __builtin_amdgcn_global_load_lds(
        (const __attribute__((address_space(1))) void*)g,
        (__attribute__((address_space(3))) void*)l, 16, 0, 0);
}

// Stage a [128][64] f16 tile (row stride 64) from global rows grow0+n,
// cols [k0,k0+64), stride EMB. Swizzle applied via the source gather.
__device__ __forceinline__ void stage64(_Float16* lds, const _Float16* gbase,
                                        int grow0, int k0, int wave, int lane) {
#pragma unroll
    for (int i = 0; i < 4; ++i) {
        int idx = wave * 256 + i * 64 + lane;   // 16B-block id, 0..1023
        int n   = idx >> 3;
        int kb  = (idx & 7) ^ (((n >> 2) & 3) << 1);
        gld_lds16(gbase + (grow0 + n) * EMB + k0 + kb * 8,
                  lds + wave * 2048 + i * 512);
    }
}

#define ZACC(A)                                   \
    _Pragma("unroll") for (int _i = 0; _i < 2; ++_i) \
    _Pragma("unroll") for (int _j = 0; _j < 8; ++_j) \
        A[_i][_j] = (f32x4){0.f, 0.f, 0.f, 0.f};

// ---------------- prep: x->f16 + 4 weight transposes, one launch ----------------
__global__ void k_prep(const float* __restrict__ x, _Float16* __restrict__ xh,
                       const float* __restrict__ Wq, const float* __restrict__ Wk,
                       const float* __restrict__ Wv, const float* __restrict__ Wo,
                       _Float16* __restrict__ Wqkvt, _Float16* __restrict__ Wot) {
    __shared__ float t[32][33];
    const int g = blockIdx.x, tid = threadIdx.x;
    if (g < 12288) {
        long i = ((long)g * 256 + tid) * 8;
        f32x4 a = *(const f32x4*)(x + i);
        f32x4 b = *(const f32x4*)(x + i + 4);
        f16x8 o;
        o[0] = (_Float16)a[0]; o[1] = (_Float16)a[1];
        o[2] = (_Float16)a[2]; o[3] = (_Float16)a[3];
        o[4] = (_Float16)b[0]; o[5] = (_Float16)b[1];
        o[6] = (_Float16)b[2]; o[7] = (_Float16)b[3];
        *(f16x8*)(xh + i) = o;
        return;
    }
    const int tb = g - 12288;            // 0..1023
    const int z = tb >> 8, t2 = tb & 255;
    const float* W = (z == 0) ? Wq : (z == 1) ? Wk : (z == 2) ? Wv : Wo;
    _Float16* Wt = (z < 3) ? (Wqkvt + (long)z * 512 * EMB) : Wot;
    const int tx = tid & 31, ty = tid >> 5;      // 32 x 8
    const int k0 = (t2 & 15) * 32, n0 = (t2 >> 4) * 32;
#pragma unroll
    for (int i = 0; i < 4; ++i)
        t[ty + i * 8][tx] = W[(k0 + ty + i * 8) * EMB + n0 + tx];
    __syncthreads();
#pragma unroll
    for (int i = 0; i < 4; ++i)
        Wt[(n0 + ty + i * 8) * EMB + k0 + tx] = (_Float16)t[tx][ty + i * 8];
}

// ---------------- QKV projection GEMM (round-4 version, m97 plateau) ----------------
__global__ __launch_bounds__(256, 4)
void k_qkv(const _Float16* __restrict__ xh, const _Float16* __restrict__ Wqkvt,
           const float* __restrict__ bq, const float* __restrict__ bk,
           const float* __restrict__ bv,
           _Float16* __restrict__ qb, _Float16* __restrict__ kb,
           _Float16* __restrict__ vtb) {
    __shared__ _Float16 S[2][128 * 64];
    _Float16* SA = S[0];
    _Float16* SB = S[1];
    const int tid = threadIdx.x, wave = tid >> 6, lane = tid & 63;
    const int l15 = lane & 15, quad = lane >> 4;
    const int g = blockIdx.x;                    // 4608 = 8 xcd * (48 bb * 12 j)
    const int xcd = g & 7, r = g >> 3;
    const int bb = xcd * 48 + r / 12, j = r % 12;
    const int m0 = bb * 128;
    const bool vswap = (j >= 8);
    const _Float16* As = vswap ? SB : SA;
    const _Float16* Bs = vswap ? SA : SB;
    f32x4 acc[2][8];
    ZACC(acc);
    for (int k0 = 0; k0 < EMB; k0 += 64) {
        stage64(SA, xh, m0, k0, wave, lane);
        stage64(SB, Wqkvt, j * 128, k0, wave, lane);
        __syncthreads();
#pragma unroll
        for (int ktl = 0; ktl < 2; ++ktl) {
            int cb = ktl * 32 + quad * 8;
            f16x8 a0 = *(const f16x8*)&As[swz64(wave * 32 + l15, cb)];
            f16x8 a1 = *(const f16x8*)&As[swz64(wave * 32 + 16 + l15, cb)];
#pragma unroll
            for (int nt = 0; nt < 8; ++nt) {
                f16x8 bbf = *(const f16x8*)&Bs[swz64(nt * 16 + l15, cb)];
                acc[0][nt] = MFMA16(a0, bbf, acc[0][nt]);
                acc[1][nt] = MFMA16(a1, bbf, acc[1][nt]);
            }
        }
        __syncthreads();
    }
    // epilogue: C (+bias) -> LDS (32 KB, swizzled) -> coalesced b128 stores
    _Float16* SC = &S[0][0];
    if (!vswap) {
        const float* bias = (j < 4) ? bq : bk;
        const int nc0 = (j & 3) * 128;
#pragma unroll
        for (int nt = 0; nt < 8; ++nt) {
            int col = nt * 16 + l15;
            float bz = bias[nc0 + col];
#pragma unroll
            for (int mt = 0; mt < 2; ++mt)
#pragma unroll
                for (int rr = 0; rr < 4; ++rr) {
                    int row = wave * 32 + mt * 16 + quad * 4 + rr;
                    SC[swz128(row, col)] = (_Float16)(acc[mt][nt][rr] + bz);
                }
        }
        __syncthreads();
        _Float16* dst = (j < 4) ? qb : kb;
#pragma unroll
        for (int i = 0; i < 8; ++i) {
            int idx = i * 256 + tid;
            int row = idx >> 4, col = (idx & 15) * 8;
            f16x8 v = *(const f16x8*)&SC[row * 128 + (col ^ (((row >> 2) & 3) << 4))];
            *(f16x8*)(dst + (long)(m0 + row) * EMB + nc0 + col) = v;
        }
    } else {
        const int hv = j - 8;
#pragma unroll
        for (int mt = 0; mt < 2; ++mt)
#pragma unroll
            for (int rr = 0; rr < 4; ++rr) {
                int row = wave * 32 + mt * 16 + quad * 4 + rr;   // row = head-dim d
                float bz = bv[hv * 128 + row];
#pragma unroll
                for (int nt = 0; nt < 8; ++nt) {
                    int col = nt * 16 + l15;                     // col = token t
                    SC[swz128(row, col)] = (_Float16)(acc[mt][nt][rr] + bz);
                }
            }
        __syncthreads();
        _Float16* dst = vtb + (long)(bb * 4 + hv) * 128 * 128;
#pragma unroll
        for (int i = 0; i < 8; ++i) {
            int idx = i * 256 + tid;
            int row = idx >> 4, col = (idx & 15) * 8;
            f16x8 v = *(const f16x8*)&SC[row * 128 + (col ^ (((row >> 2) & 3) << 4))];
            *(f16x8*)(dst + row * 128 + col) = v;
        }
    }
}

// ---------------- attention core: one 512-thread block per (b,h) ----------------
// 32 KB LDS (K -> P -> O in one buffer), V fragments straight from global
// (block-private 32 KB panel, L1/L2-resident). 3 blocks/CU via
// __launch_bounds__(512,6). Q prefetched to regs; setprio around MFMA.
__global__ __launch_bounds__(512, 6)
void k_core(const _Float16* __restrict__ qb, const _Float16* __restrict__ kb,
            const _Float16* __restrict__ vtb, _Float16* __restrict__ attn) {
    __shared__ _Float16 SK[128 * 128];   // 32 KB: K -> P -> O
    const int tid = threadIdx.x, wave = tid >> 6, lane = tid & 63;
    const int l15 = lane & 15, quad = lane >> 4;
    const int g = blockIdx.x;                    // 1536 = 8 xcd * (48 b * 4 h)
    const int xcd = g & 7, r = g >> 3;
    const int b = xcd * 48 + (r >> 2), h = r & 3;
    const int sRow0 = b * 128, wRow0 = h * 128;
    const _Float16* vt = vtb + (long)(b * 4 + h) * 128 * 128;

    // ---- Q prefetch (4 loads)
    f16x8 qf[4];
#pragma unroll
    for (int kt = 0; kt < 4; ++kt)
        qf[kt] = *(const f16x8*)(qb + (long)(sRow0 + wave * 16 + l15) * EMB +
                                 wRow0 + kt * 32 + quad * 8);
    __builtin_amdgcn_sched_barrier(0);
    // ---- stage K (4 gld_lds/thread, 32 KB)
#pragma unroll
    for (int i = 0; i < 4; ++i) {
        int seg = i * 8 + wave;                  // 0..31
        int idx = seg * 64 + lane;               // 0..2047
        int n   = idx >> 4;
        int kbk = (idx & 15) ^ (((n >> 2) & 3) << 1);
        gld_lds16(kb + (long)(sRow0 + n) * EMB + wRow0 + kbk * 8, SK + seg * 512);
    }
    asm volatile("s_waitcnt vmcnt(0)" ::: "memory");
    __builtin_amdgcn_sched_barrier(0);
    __builtin_amdgcn_s_barrier();

    f32x4 acc[8];
#pragma unroll
    for (int nt = 0; nt < 8; ++nt) acc[nt] = (f32x4){0.f, 0.f, 0.f, 0.f};

    // ---- scores = Q K^T (wave owns rows wave*16..+16)
    __builtin_amdgcn_s_setprio(1);
#pragma unroll
    for (int kt = 0; kt < 4; ++kt) {
        int ca = kt * 32 + quad * 8;
#pragma unroll
        for (int nt = 0; nt < 8; ++nt) {
            f16x8 kf = *(const f16x8*)&SK[swz128(nt * 16 + l15, ca)];
            acc[nt] = MFMA16(qf[kt], kf, acc[nt]);
        }
    }
    __builtin_amdgcn_s_setprio(0);
    // ---- softmax over t (row in the 16 lanes of a quad-row)
#pragma unroll
    for (int rr = 0; rr < 4; ++rr) {
        float mx = acc[0][rr];
#pragma unroll
        for (int nt = 1; nt < 8; ++nt) mx = fmaxf(mx, acc[nt][rr]);
        mx = fmaxf(mx, __shfl_xor(mx, 1));
        mx = fmaxf(mx, __shfl_xor(mx, 2));
        mx = fmaxf(mx, __shfl_xor(mx, 4));
        mx = fmaxf(mx, __shfl_xor(mx, 8));
        float sm = 0.f;
#pragma unroll
        for (int nt = 0; nt < 8; ++nt) {
            float e = __expf(acc[nt][rr] - mx);
            acc[nt][rr] = e;
            sm += e;
        }
        sm += __shfl_xor(sm, 1);
        sm += __shfl_xor(sm, 2);
        sm += __shfl_xor(sm, 4);
        sm += __shfl_xor(sm, 8);
        float inv = 1.0f / sm;
#pragma unroll
        for (int nt = 0; nt < 8; ++nt) acc[nt][rr] *= inv;
    }
    __syncthreads();   // all QK^T reads of SK (K) done -> safe to overwrite with P

    // ---- P -> SK (C-layout -> A-layout; band rows wave*16..+15 are
    //      written and read by THIS wave only -> wave-local wait suffices)
#pragma unroll
    for (int nt = 0; nt < 8; ++nt) {
        int col = nt * 16 + l15;
#pragma unroll
        for (int rr = 0; rr < 4; ++rr)
            SK[swz128(wave * 16 + quad * 4 + rr, col)] = (_Float16)acc[nt][rr];
    }
    asm volatile("s_waitcnt lgkmcnt(0)" ::: "memory");
    __builtin_amdgcn_sched_barrier(0);

    // ---- O = P @ V  (A = P from SK band, B = V^T rows straight from global)
#pragma unroll
    for (int nt = 0; nt < 8; ++nt) acc[nt] = (f32x4){0.f, 0.f, 0.f, 0.f};
    __builtin_amdgcn_s_setprio(1);
#pragma unroll
    for (int kt = 0; kt < 4; ++kt) {
        int ca = kt * 32 + quad * 8;
        f16x8 p0 = *(const f16x8*)&SK[swz128(wave * 16 + l15, ca)];
#pragma unroll
        for (int nt = 0; nt < 8; ++nt) {
            f16x8 vf = *(const f16x8*)(vt + (nt * 16 + l15) * 128 + ca);
            acc[nt] = MFMA16(p0, vf, acc[nt]);
        }
    }
    __builtin_amdgcn_s_setprio(0);
    asm volatile("s_waitcnt lgkmcnt(0)" ::: "memory");   // PV reads of P band done
    __builtin_amdgcn_sched_barrier(0);

    // ---- O -> SK (wave-local band), then coalesced b128 stores
#pragma unroll
    for (int nt = 0; nt < 8; ++nt) {
        int col = nt * 16 + l15;
#pragma unroll
        for (int rr = 0; rr < 4; ++rr)
            SK[swz128(wave * 16 + quad * 4 + rr, col)] = (_Float16)acc[nt][rr];
    }
    __syncthreads();
#pragma unroll
    for (int i = 0; i < 4; ++i) {
        int idx = i * 512 + tid;
        int row = idx >> 4, col = (idx & 15) * 8;
        f16x8 v = *(const f16x8*)&SK[row * 128 + (col ^ (((row >> 2) & 3) << 4))];
        *(f16x8*)(attn + (long)(sRow0 + row) * EMB + wRow0 + col) = v;
    }
}

// ---------------- output projection: out = attn @ Wo + bo (fp32) ----------------
// k_qkv-structure clone: 128x128 tiles, grid 1536 = 8 xcd * (48 m * 4 n).
// Epilogue: two fp32 passes (64x128 = 32 KB LDS each) -> coalesced f32x4.
__global__ __launch_bounds__(256, 4)
void k_out(const _Float16* __restrict__ attn, const _Float16* __restrict__ Wot,
           const float* __restrict__ bo, float* __restrict__ out) {
    __shared__ _Float16 S[2][128 * 64];
    _Float16* SA = S[0];
    _Float16* SB = S[1];
    const int tid = threadIdx.x, wave = tid >> 6, lane = tid & 63;
    const int l15 = lane & 15, quad = lane >> 4;
    const int g = blockIdx.x;                    // 1536 = 8 xcd * (48 m * 4 n)
    const int xcd = g & 7, r = g >> 3;
    const int m0 = (xcd * 48 + (r >> 2)) * 128, n0 = (r & 3) * 128;
    f32x4 acc[2][8];
    ZACC(acc);
    for (int k0 = 0; k0 < EMB; k0 += 64) {
        stage64(SA, attn, m0, k0, wave, lane);
        stage64(SB, Wot, n0, k0, wave, lane);
        __syncthreads();
#pragma unroll
        for (int ktl = 0; ktl < 2; ++ktl) {
            int cb = ktl * 32 + quad * 8;
            f16x8 a0 = *(const f16x8*)&SA[swz64(wave * 32 + l15, cb)];
            f16x8 a1 = *(const f16x8*)&SA[swz64(wave * 32 + 16 + l15, cb)];
#pragma unroll
            for (int nt = 0; nt < 8; ++nt) {
                f16x8 bbf = *(const f16x8*)&SB[swz64(nt * 16 + l15, cb)];
                acc[0][nt] = MFMA16(a0, bbf, acc[0][nt]);
                acc[1][nt] = MFMA16(a1, bbf, acc[1][nt]);
            }
        }
        __syncthreads();
    }
    // epilogue: acc (+bias) -> fp32 LDS, two 64-row passes, quad-parity xor
    float* SF = (float*)&S[0][0];
    float bz[8];
#pragma unroll
    for (int nt = 0; nt < 8; ++nt) bz[nt] = bo[n0 + nt * 16 + l15];
#pragma unroll
    for (int mt = 0; mt < 2; ++mt) {
#pragma unroll
        for (int nt = 0; nt < 8; ++nt) {
            int col = nt * 16 + l15;
#pragma unroll
            for (int rr = 0; rr < 4; ++rr) {
                int lr = wave * 16 + quad * 4 + rr;        // 0..63
                SF[lr * 128 + (col ^ (((lr >> 2) & 1) << 4))] = acc[mt][nt][rr] + bz[nt];
            }
        }
        __syncthreads();
#pragma unroll
        for (int i = 0; i < 8; ++i) {
            int idx = i * 256 + tid;
            int lr = idx >> 5, c4 = (idx & 31) * 4;
            f32x4 v = *(const f32x4*)&SF[lr * 128 + (c4 ^ (((lr >> 2) & 1) << 4))];
            int grow = (lr >> 4) * 32 + mt * 16 + (lr & 15);
            *(f32x4*)(out + (long)(m0 + grow) * EMB + n0 + c4) = v;
        }
        __syncthreads();
    }
}

extern "C" void kernel_launch(void* const* d_in, const int* in_sizes, int n_in,
                              void* d_out, int out_size, void* d_ws, size_t ws_size,
                              hipStream_t stream) {
    const float* x  = (const float*)d_in[0];
    const float* Wq = (const float*)d_in[1];
    const float* bq = (const float*)d_in[2];
    const float* Wk = (const float*)d_in[3];
    const float* bk = (const float*)d_in[4];
    const float* Wv = (const float*)d_in[5];
    const float* bv = (const float*)d_in[6];
    const float* Wo = (const float*)d_in[7];
    const float* bo = (const float*)d_in[8];
    float* out = (float*)d_out;

    // ws layout (bytes). attn ALIASES xh (xh dead after k_qkv). Peak ~203.4 MB.
    char* w = (char*)d_ws;
    _Float16* xh    = (_Float16*)(w);                       // 50,331,648 B
    _Float16* attn  = xh;                                   // alias
    _Float16* Wqkvt = (_Float16*)(w + 50331648);            //  1,572,864 B (Wq|Wk|Wv)^T
    _Float16* Wot   = (_Float16*)(w + 51904512);            //    524,288 B
    _Float16* qb    = (_Float16*)(w + 52428800);            // 50,331,648 B
    _Float16* kb    = (_Float16*)(w + 102760448);           // 50,331,648 B
    _Float16* vtb   = (_Float16*)(w + 153092096);           // 50,331,648 B -> end 203,423,744

    k_prep<<<13312, 256, 0, stream>>>(x, xh, Wq, Wk, Wv, Wo, Wqkvt, Wot);
    k_qkv<<<4608, 256, 0, stream>>>(xh, Wqkvt, bq, bk, bv, qb, kb, vtb);
    k_core<<<1536, 512, 0, stream>>>(qb, kb, vtb, attn);
    k_out<<<1536, 256, 0, stream>>>(attn, Wot, bo, out);
}

// Round 6
// 357.313 us; speedup vs baseline: 1.0489x; 1.0489x over previous
//
#include <hip/hip_runtime.h>
#include <hip/hip_bf16.h>
#include <cstdint>

// B=384, S=128, E=512, H=4, D=128. out = softmax((x Wq)(x Wk)^T) (x Wv) Wo
// Round 10: k_core REVERTED to round-8 form (362.6 us winner) - round-9's
// V-from-global regressed +12 us (lane stride 256 B -> uncoalesced PV
// fragment reads; staging exists to coalesce them). One micro kept: k_qkv/
// k_out staging swizzle upgraded 2-bit -> 3-bit key (16 fragment rows -> 8
// distinct 16B slots = 2-way = free; pair verified in round-1's k_qkv2,
// which measured SQ_LDS_BANK_CONFLICT = 0). k_core swizzles untouched.

#define EMB 512

typedef __attribute__((ext_vector_type(4))) float    f32x4;
typedef __attribute__((ext_vector_type(8))) _Float16 f16x8;

#define MFMA16(a, b, c) __builtin_amdgcn_mfma_f32_16x16x32_f16((a), (b), (c), 0, 0, 0)

// 2-bit-key XOR swizzle for [*][128] tiles (k_core staging + epilogues).
__device__ __forceinline__ int swz128(int row, int col) {
    return row * 128 + (col ^ (((row >> 2) & 3) << 4));
}
// 3-bit-key XOR swizzle for [*][64] staged tiles (k_qkv/k_out): 16
// consecutive fragment rows -> 8 distinct 16B slots = 2-way = free.
__device__ __forceinline__ int swz64(int row, int col) {
    return row * 64 + (col ^ ((row & 7) << 3));
}

__device__ __forceinline__ void gld_lds16(const _Float16* g, _Float16* l) {
    __builtin_amdgcn_global_load_lds(
        (const __attribute__((address_space(1))) void*)g,
        (__attribute__((address_space(3))) void*)l, 16, 0, 0);
}

// Stage a [128][64] f16 tile (row stride 64) from global rows grow0+n,
// cols [k0,k0+64), stride EMB. 3-bit swizzle applied via the source gather
// (LDS dest stays linear - guide rule 21).
__device__ __forceinline__ void stage64(_Float16* lds, const _Float16* gbase,
                                        int grow0, int k0, int wave, int lane) {
#pragma unroll
    for (int i = 0; i < 4; ++i) {
        int idx = wave * 256 + i * 64 + lane;   // 16B-block id, 0..1023
        int n   = idx >> 3;
        int kb  = (idx & 7) ^ (n & 7);
        gld_lds16(gbase + (grow0 + n) * EMB + k0 + kb * 8,
                  lds + wave * 2048 + i * 512);
    }
}

#define ZACC(A)                                   \
    _Pragma("unroll") for (int _i = 0; _i < 2; ++_i) \
    _Pragma("unroll") for (int _j = 0; _j < 8; ++_j) \
        A[_i][_j] = (f32x4){0.f, 0.f, 0.f, 0.f};

// ---------------- prep: x->f16 + 4 weight transposes, one launch ----------------
__global__ void k_prep(const float* __restrict__ x, _Float16* __restrict__ xh,
                       const float* __restrict__ Wq, const float* __restrict__ Wk,
                       const float* __restrict__ Wv, const float* __restrict__ Wo,
                       _Float16* __restrict__ Wqkvt, _Float16* __restrict__ Wot) {
    __shared__ float t[32][33];
    const int g = blockIdx.x, tid = threadIdx.x;
    if (g < 12288) {
        long i = ((long)g * 256 + tid) * 8;
        f32x4 a = *(const f32x4*)(x + i);
        f32x4 b = *(const f32x4*)(x + i + 4);
        f16x8 o;
        o[0] = (_Float16)a[0]; o[1] = (_Float16)a[1];
        o[2] = (_Float16)a[2]; o[3] = (_Float16)a[3];
        o[4] = (_Float16)b[0]; o[5] = (_Float16)b[1];
        o[6] = (_Float16)b[2]; o[7] = (_Float16)b[3];
        *(f16x8*)(xh + i) = o;
        return;
    }
    const int tb = g - 12288;            // 0..1023
    const int z = tb >> 8, t2 = tb & 255;
    const float* W = (z == 0) ? Wq : (z == 1) ? Wk : (z == 2) ? Wv : Wo;
    _Float16* Wt = (z < 3) ? (Wqkvt + (long)z * 512 * EMB) : Wot;
    const int tx = tid & 31, ty = tid >> 5;      // 32 x 8
    const int k0 = (t2 & 15) * 32, n0 = (t2 >> 4) * 32;
#pragma unroll
    for (int i = 0; i < 4; ++i)
        t[ty + i * 8][tx] = W[(k0 + ty + i * 8) * EMB + n0 + tx];
    __syncthreads();
#pragma unroll
    for (int i = 0; i < 4; ++i)
        Wt[(n0 + ty + i * 8) * EMB + k0 + tx] = (_Float16)t[tx][ty + i * 8];
}

// ---------------- QKV projection GEMM (m97 structure, 3-bit staging swizzle) --------
__global__ __launch_bounds__(256, 4)
void k_qkv(const _Float16* __restrict__ xh, const _Float16* __restrict__ Wqkvt,
           const float* __restrict__ bq, const float* __restrict__ bk,
           const float* __restrict__ bv,
           _Float16* __restrict__ qb, _Float16* __restrict__ kb,
           _Float16* __restrict__ vtb) {
    __shared__ _Float16 S[2][128 * 64];
    _Float16* SA = S[0];
    _Float16* SB = S[1];
    const int tid = threadIdx.x, wave = tid >> 6, lane = tid & 63;
    const int l15 = lane & 15, quad = lane >> 4;
    const int g = blockIdx.x;                    // 4608 = 8 xcd * (48 bb * 12 j)
    const int xcd = g & 7, r = g >> 3;
    const int bb = xcd * 48 + r / 12, j = r % 12;
    const int m0 = bb * 128;
    const bool vswap = (j >= 8);
    const _Float16* As = vswap ? SB : SA;
    const _Float16* Bs = vswap ? SA : SB;
    f32x4 acc[2][8];
    ZACC(acc);
    for (int k0 = 0; k0 < EMB; k0 += 64) {
        stage64(SA, xh, m0, k0, wave, lane);
        stage64(SB, Wqkvt, j * 128, k0, wave, lane);
        __syncthreads();
#pragma unroll
        for (int ktl = 0; ktl < 2; ++ktl) {
            int cb = ktl * 32 + quad * 8;
            f16x8 a0 = *(const f16x8*)&As[swz64(wave * 32 + l15, cb)];
            f16x8 a1 = *(const f16x8*)&As[swz64(wave * 32 + 16 + l15, cb)];
#pragma unroll
            for (int nt = 0; nt < 8; ++nt) {
                f16x8 bbf = *(const f16x8*)&Bs[swz64(nt * 16 + l15, cb)];
                acc[0][nt] = MFMA16(a0, bbf, acc[0][nt]);
                acc[1][nt] = MFMA16(a1, bbf, acc[1][nt]);
            }
        }
        __syncthreads();
    }
    // epilogue: C (+bias) -> LDS (32 KB, swizzled) -> coalesced b128 stores
    _Float16* SC = &S[0][0];
    if (!vswap) {
        const float* bias = (j < 4) ? bq : bk;
        const int nc0 = (j & 3) * 128;
#pragma unroll
        for (int nt = 0; nt < 8; ++nt) {
            int col = nt * 16 + l15;
            float bz = bias[nc0 + col];
#pragma unroll
            for (int mt = 0; mt < 2; ++mt)
#pragma unroll
                for (int rr = 0; rr < 4; ++rr) {
                    int row = wave * 32 + mt * 16 + quad * 4 + rr;
                    SC[swz128(row, col)] = (_Float16)(acc[mt][nt][rr] + bz);
                }
        }
        __syncthreads();
        _Float16* dst = (j < 4) ? qb : kb;
#pragma unroll
        for (int i = 0; i < 8; ++i) {
            int idx = i * 256 + tid;
            int row = idx >> 4, col = (idx & 15) * 8;
            f16x8 v = *(const f16x8*)&SC[row * 128 + (col ^ (((row >> 2) & 3) << 4))];
            *(f16x8*)(dst + (long)(m0 + row) * EMB + nc0 + col) = v;
        }
    } else {
        const int hv = j - 8;
#pragma unroll
        for (int mt = 0; mt < 2; ++mt)
#pragma unroll
            for (int rr = 0; rr < 4; ++rr) {
                int row = wave * 32 + mt * 16 + quad * 4 + rr;   // row = head-dim d
                float bz = bv[hv * 128 + row];
#pragma unroll
                for (int nt = 0; nt < 8; ++nt) {
                    int col = nt * 16 + l15;                     // col = token t
                    SC[swz128(row, col)] = (_Float16)(acc[mt][nt][rr] + bz);
                }
            }
        __syncthreads();
        _Float16* dst = vtb + (long)(bb * 4 + hv) * 128 * 128;
#pragma unroll
        for (int i = 0; i < 8; ++i) {
            int idx = i * 256 + tid;
            int row = idx >> 4, col = (idx & 15) * 8;
            f16x8 v = *(const f16x8*)&SC[row * 128 + (col ^ (((row >> 2) & 3) << 4))];
            *(f16x8*)(dst + row * 128 + col) = v;
        }
    }
}

// ---------------- attention core: one 512-thread block per (b,h) ----------------
// Round-8 version (362.6 us winner): Q prefetch to regs, K/V staged via
// gld_lds with counted vmcnt(4) barrier (QK^T overlaps V staging), setprio
// around MFMA clusters, wave-local P barrier.
__global__ __launch_bounds__(512, 4)
void k_core(const _Float16* __restrict__ qb, const _Float16* __restrict__ kb,
            const _Float16* __restrict__ vtb, _Float16* __restrict__ attn) {
    __shared__ _Float16 SK[128 * 128];   // K -> P
    __shared__ _Float16 SV[128 * 128];   // V^T -> O
    const int tid = threadIdx.x, wave = tid >> 6, lane = tid & 63;
    const int l15 = lane & 15, quad = lane >> 4;
    const int g = blockIdx.x;                    // 1536 = 8 xcd * (48 b * 4 h)
    const int xcd = g & 7, r = g >> 3;
    const int b = xcd * 48 + (r >> 2), h = r & 3;
    const int sRow0 = b * 128, wRow0 = h * 128;
    const _Float16* vt = vtb + (long)(b * 4 + h) * 128 * 128;

    // ---- Q prefetch (4 loads, oldest in vmcnt ledger)
    f16x8 qf[4];
#pragma unroll
    for (int kt = 0; kt < 4; ++kt)
        qf[kt] = *(const f16x8*)(qb + (long)(sRow0 + wave * 16 + l15) * EMB +
                                 wRow0 + kt * 32 + quad * 8);
    __builtin_amdgcn_sched_barrier(0);
    // ---- stage K (4 gld_lds/thread)
#pragma unroll
    for (int i = 0; i < 4; ++i) {
        int seg = i * 8 + wave;                  // 0..31
        int idx = seg * 64 + lane;               // 0..2047
        int n   = idx >> 4;
        int kbk = (idx & 15) ^ (((n >> 2) & 3) << 1);
        gld_lds16(kb + (long)(sRow0 + n) * EMB + wRow0 + kbk * 8, SK + seg * 512);
    }
    __builtin_amdgcn_sched_barrier(0);
    // ---- stage V^T (4 gld_lds/thread, newest 4 in ledger)
#pragma unroll
    for (int i = 0; i < 4; ++i) {
        int seg = i * 8 + wave;
        int idx = seg * 64 + lane;
        int n   = idx >> 4;
        int kbk = (idx & 15) ^ (((n >> 2) & 3) << 1);
        gld_lds16(vt + n * 128 + kbk * 8, SV + seg * 512);
    }
    // counted wait: completes Q(4)+K(4); V(4) stays in flight under QK^T.
    asm volatile("s_waitcnt vmcnt(4)" ::: "memory");
    __builtin_amdgcn_sched_barrier(0);
    __builtin_amdgcn_s_barrier();

    f32x4 acc[8];
#pragma unroll
    for (int nt = 0; nt < 8; ++nt) acc[nt] = (f32x4){0.f, 0.f, 0.f, 0.f};

    // ---- scores = Q K^T (wave owns rows wave*16..+16)
    __builtin_amdgcn_s_setprio(1);
#pragma unroll
    for (int kt = 0; kt < 4; ++kt) {
        int ca = kt * 32 + quad * 8;
#pragma unroll
        for (int nt = 0; nt < 8; ++nt) {
            f16x8 kf = *(const f16x8*)&SK[swz128(nt * 16 + l15, ca)];
            acc[nt] = MFMA16(qf[kt], kf, acc[nt]);
        }
    }
    __builtin_amdgcn_s_setprio(0);
    // ---- softmax over t (row in the 16 lanes of a quad-row)
#pragma unroll
    for (int rr = 0; rr < 4; ++rr) {
        float mx = acc[0][rr];
#pragma unroll
        for (int nt = 1; nt < 8; ++nt) mx = fmaxf(mx, acc[nt][rr]);
        mx = fmaxf(mx, __shfl_xor(mx, 1));
        mx = fmaxf(mx, __shfl_xor(mx, 2));
        mx = fmaxf(mx, __shfl_xor(mx, 4));
        mx = fmaxf(mx, __shfl_xor(mx, 8));
        float sm = 0.f;
#pragma unroll
        for (int nt = 0; nt < 8; ++nt) {
            float e = __expf(acc[nt][rr] - mx);
            acc[nt][rr] = e;
            sm += e;
        }
        sm += __shfl_xor(sm, 1);
        sm += __shfl_xor(sm, 2);
        sm += __shfl_xor(sm, 4);
        sm += __shfl_xor(sm, 8);
        float inv = 1.0f / sm;
#pragma unroll
        for (int nt = 0; nt < 8; ++nt) acc[nt][rr] *= inv;
    }
    __syncthreads();   // all QK^T reads of SK done (also drains V: vmcnt(0))

    // ---- P -> SK (C-layout -> A-layout; band rows wave*16..+15 are
    //      written and read by THIS wave only -> wave-local wait suffices)
#pragma unroll
    for (int nt = 0; nt < 8; ++nt) {
        int col = nt * 16 + l15;
#pragma unroll
        for (int rr = 0; rr < 4; ++rr)
            SK[swz128(wave * 16 + quad * 4 + rr, col)] = (_Float16)acc[nt][rr];
    }
    asm volatile("s_waitcnt lgkmcnt(0)" ::: "memory");
    __builtin_amdgcn_sched_barrier(0);

    // ---- O = P @ V  (B[k=t][n=d] = SV row d, contiguous t)
#pragma unroll
    for (int nt = 0; nt < 8; ++nt) acc[nt] = (f32x4){0.f, 0.f, 0.f, 0.f};
    __builtin_amdgcn_s_setprio(1);
#pragma unroll
    for (int kt = 0; kt < 4; ++kt) {
        int ca = kt * 32 + quad * 8;
        f16x8 p0 = *(const f16x8*)&SK[swz128(wave * 16 + l15, ca)];
#pragma unroll
        for (int nt = 0; nt < 8; ++nt) {
            f16x8 vf = *(const f16x8*)&SV[swz128(nt * 16 + l15, ca)];
            acc[nt] = MFMA16(p0, vf, acc[nt]);
        }
    }
    __builtin_amdgcn_s_setprio(0);
    __syncthreads();   // all PV reads of SV done

    // ---- O -> SV, then coalesced b128 stores
#pragma unroll
    for (int nt = 0; nt < 8; ++nt) {
        int col = nt * 16 + l15;
#pragma unroll
        for (int rr = 0; rr < 4; ++rr)
            SV[swz128(wave * 16 + quad * 4 + rr, col)] = (_Float16)acc[nt][rr];
    }
    __syncthreads();
#pragma unroll
    for (int i = 0; i < 4; ++i) {
        int idx = i * 512 + tid;
        int row = idx >> 4, col = (idx & 15) * 8;
        f16x8 v = *(const f16x8*)&SV[row * 128 + (col ^ (((row >> 2) & 3) << 4))];
        *(f16x8*)(attn + (long)(sRow0 + row) * EMB + wRow0 + col) = v;
    }
}

// ---------------- output projection: out = attn @ Wo + bo (fp32) ----------------
// k_qkv-structure clone: 128x128 tiles, grid 1536 = 8 xcd * (48 m * 4 n).
// Epilogue: two fp32 passes (64x128 = 32 KB LDS each) -> coalesced f32x4.
__global__ __launch_bounds__(256, 4)
void k_out(const _Float16* __restrict__ attn, const _Float16* __restrict__ Wot,
           const float* __restrict__ bo, float* __restrict__ out) {
    __shared__ _Float16 S[2][128 * 64];
    _Float16* SA = S[0];
    _Float16* SB = S[1];
    const int tid = threadIdx.x, wave = tid >> 6, lane = tid & 63;
    const int l15 = lane & 15, quad = lane >> 4;
    const int g = blockIdx.x;                    // 1536 = 8 xcd * (48 m * 4 n)
    const int xcd = g & 7, r = g >> 3;
    const int m0 = (xcd * 48 + (r >> 2)) * 128, n0 = (r & 3) * 128;
    f32x4 acc[2][8];
    ZACC(acc);
    for (int k0 = 0; k0 < EMB; k0 += 64) {
        stage64(SA, attn, m0, k0, wave, lane);
        stage64(SB, Wot, n0, k0, wave, lane);
        __syncthreads();
#pragma unroll
        for (int ktl = 0; ktl < 2; ++ktl) {
            int cb = ktl * 32 + quad * 8;
            f16x8 a0 = *(const f16x8*)&SA[swz64(wave * 32 + l15, cb)];
            f16x8 a1 = *(const f16x8*)&SA[swz64(wave * 32 + 16 + l15, cb)];
#pragma unroll
            for (int nt = 0; nt < 8; ++nt) {
                f16x8 bbf = *(const f16x8*)&SB[swz64(nt * 16 + l15, cb)];
                acc[0][nt] = MFMA16(a0, bbf, acc[0][nt]);
                acc[1][nt] = MFMA16(a1, bbf, acc[1][nt]);
            }
        }
        __syncthreads();
    }
    // epilogue: acc (+bias) -> fp32 LDS, two 64-row passes, quad-parity xor
    float* SF = (float*)&S[0][0];
    float bz[8];
#pragma unroll
    for (int nt = 0; nt < 8; ++nt) bz[nt] = bo[n0 + nt * 16 + l15];
#pragma unroll
    for (int mt = 0; mt < 2; ++mt) {
#pragma unroll
        for (int nt = 0; nt < 8; ++nt) {
            int col = nt * 16 + l15;
#pragma unroll
            for (int rr = 0; rr < 4; ++rr) {
                int lr = wave * 16 + quad * 4 + rr;        // 0..63
                SF[lr * 128 + (col ^ (((lr >> 2) & 1) << 4))] = acc[mt][nt][rr] + bz[nt];
            }
        }
        __syncthreads();
#pragma unroll
        for (int i = 0; i < 8; ++i) {
            int idx = i * 256 + tid;
            int lr = idx >> 5, c4 = (idx & 31) * 4;
            f32x4 v = *(const f32x4*)&SF[lr * 128 + (c4 ^ (((lr >> 2) & 1) << 4))];
            int grow = (lr >> 4) * 32 + mt * 16 + (lr & 15);
            *(f32x4*)(out + (long)(m0 + grow) * EMB + n0 + c4) = v;
        }
        __syncthreads();
    }
}

extern "C" void kernel_launch(void* const* d_in, const int* in_sizes, int n_in,
                              void* d_out, int out_size, void* d_ws, size_t ws_size,
                              hipStream_t stream) {
    const float* x  = (const float*)d_in[0];
    const float* Wq = (const float*)d_in[1];
    const float* bq = (const float*)d_in[2];
    const float* Wk = (const float*)d_in[3];
    const float* bk = (const float*)d_in[4];
    const float* Wv = (const float*)d_in[5];
    const float* bv = (const float*)d_in[6];
    const float* Wo = (const float*)d_in[7];
    const float* bo = (const float*)d_in[8];
    float* out = (float*)d_out;

    // ws layout (bytes). attn ALIASES xh (xh dead after k_qkv). Peak ~203.4 MB.
    char* w = (char*)d_ws;
    _Float16* xh    = (_Float16*)(w);                       // 50,331,648 B
    _Float16* attn  = xh;                                   // alias
    _Float16* Wqkvt = (_Float16*)(w + 50331648);            //  1,572,864 B (Wq|Wk|Wv)^T
    _Float16* Wot   = (_Float16*)(w + 51904512);            //    524,288 B
    _Float16* qb    = (_Float16*)(w + 52428800);            // 50,331,648 B
    _Float16* kb    = (_Float16*)(w + 102760448);           // 50,331,648 B
    _Float16* vtb   = (_Float16*)(w + 153092096);           // 50,331,648 B -> end 203,423,744

    k_prep<<<13312, 256, 0, stream>>>(x, xh, Wq, Wk, Wv, Wo, Wqkvt, Wot);
    k_qkv<<<4608, 256, 0, stream>>>(xh, Wqkvt, bq, bk, bv, qb, kb, vtb);
    k_core<<<1536, 512, 0, stream>>>(qb, kb, vtb, attn);
    k_out<<<1536, 256, 0, stream>>>(attn, Wot, bo, out);
}